// Round 5
// baseline (1147.536 us; speedup 1.0000x reference)
//
#include <hip/hip_runtime.h>
#include <hip/hip_bf16.h>
#include <math.h>

#define NN 50000
#define EE 800000
#define HID 128
#define PED 24
#define IND 64
#define OUTD 64
#define EBLK 128         // edges per edge-kernel block (2 passes of 64 in epilogue)
#define AKS 136          // act/W LDS k-stride in bf16 (272 B: 16B-aligned, bank-spread)
#define XNB 32           // nodes per xh block
#define ONB 64           // nodes per out block

typedef short bf16x8 __attribute__((ext_vector_type(8)));
typedef float f32x4 __attribute__((ext_vector_type(4)));

// GELU tanh-form via sigmoid: x * sigmoid(1.5957691x + 0.07135481x^3).
// max |err| vs exact-erf GELU ~4e-4 (below bf16 noise); 6 VALU + 2 trans.
__device__ __forceinline__ float gelu_fast(float x) {
    float x2 = x * x;
    float t = __builtin_fmaf(x2, -0.07135481627f, -1.5957691216f);
    float e = __expf(x * t);
    return x * __builtin_amdgcn_rcpf(1.0f + e);
}
__device__ __forceinline__ unsigned short f2bf(float f) {
    unsigned int u = __float_as_uint(f);
    u = (u + 0x7fffu + ((u >> 16) & 1u)) >> 16;   // RNE
    return (unsigned short)u;
}
__device__ __forceinline__ unsigned int pkbf2(float a, float b) {
    __hip_bfloat162 h = __float22bfloat162_rn(make_float2(a, b));  // a -> low
    return *reinterpret_cast<unsigned int*>(&h);
}
__device__ __forceinline__ float bflo(unsigned int u) {
    return __uint_as_float(u << 16);
}
__device__ __forceinline__ float bfhi(unsigned int u) {
    return __uint_as_float(u & 0xffff0000u);
}

// ---------------------------------------------------------------------------
// Fused pre-pass:
//   blocks [0, 1563):        xh = bf16(x @ W_x + b_x), reg-tiled 4 nodes x
//                            4 ch per thread, W_x LDS-staged; zero wV slab
//   blocks [1563, 1563+208): weight transposes WT_* AND zero cnt
// ---------------------------------------------------------------------------
#define XHB ((NN + XNB - 1) / XNB)   // 1563
__global__ __launch_bounds__(256) void pre_kernel(
    const float* __restrict__ x, const float* __restrict__ W_x,
    const float* __restrict__ b_x, unsigned short* __restrict__ xhb,
    const float* __restrict__ W_in, const float* __restrict__ W1,
    const float* __restrict__ W2, const float* __restrict__ Wf,
    unsigned short* __restrict__ WT_in, unsigned short* __restrict__ WT1,
    unsigned short* __restrict__ WT2, unsigned short* __restrict__ WTf,
    float* __restrict__ wV, int* __restrict__ cnt) {
    int bx = blockIdx.x;
    int tid = threadIdx.x;
    if (bx < XHB) {
        __shared__ float s_Wx[IND * HID];     // 32 KB
        // stage W_x (64x128 f32), coalesced
#pragma unroll
        for (int i = 0; i < 8; i++) {
            int idx = tid + i * 256;          // 2048 float4
            *(float4*)&s_Wx[idx * 4] = *(const float4*)&W_x[idx * 4];
        }
        // zero wV slab for this block's nodes (32 nodes * 128 ch)
#pragma unroll
        for (int i = 0; i < 4; i++) {
            int idx = tid + i * 256;          // 1024 float4
            int n = bx * XNB + (idx >> 5);
            if (n < NN)
                *(float4*)&wV[(size_t)n * HID + (idx & 31) * 4] =
                    make_float4(0.f, 0.f, 0.f, 0.f);
        }
        __syncthreads();
        const int g = tid >> 5;               // node group 0..7
        const int q = tid & 31;               // channel quad: ch = q*4
        const int nb = bx * XNB + g * 4;
        float4 bb = *(const float4*)&b_x[q * 4];
        f32x4 acc[4];
        int nc[4];
#pragma unroll
        for (int j = 0; j < 4; j++) {
            acc[j] = (f32x4){bb.x, bb.y, bb.z, bb.w};
            int n = nb + j;
            nc[j] = n < NN ? n : NN - 1;      // clamp OOB reads
        }
#pragma unroll
        for (int k4 = 0; k4 < 16; k4++) {
            float4 xv[4];
#pragma unroll
            for (int j = 0; j < 4; j++)
                xv[j] = *(const float4*)&x[(size_t)nc[j] * IND + k4 * 4];
#pragma unroll
            for (int kk = 0; kk < 4; kk++) {
                float4 w4 = *(const float4*)&s_Wx[(k4 * 4 + kk) * HID + q * 4];
#pragma unroll
                for (int j = 0; j < 4; j++) {
                    float xs = ((const float*)&xv[j])[kk];
                    acc[j][0] += xs * w4.x; acc[j][1] += xs * w4.y;
                    acc[j][2] += xs * w4.z; acc[j][3] += xs * w4.w;
                }
            }
        }
#pragma unroll
        for (int j = 0; j < 4; j++) {
            int n = nb + j;
            if (n < NN) {
                uint2 p;
                p.x = pkbf2(acc[j][0], acc[j][1]);
                p.y = pkbf2(acc[j][2], acc[j][3]);
                *(uint2*)&xhb[(size_t)n * HID + q * 4] = p;
            }
        }
    } else {
        int idx = (bx - XHB) * 256 + tid;     // [0, 53248)
        if (idx < NN) cnt[idx] = 0;
        if (idx < 4096) {                     // WT_in [128][32], k>=24 zero-pad
            int j = idx >> 5, k = idx & 31;
            WT_in[idx] = f2bf(k < PED ? W_in[k * HID + j] : 0.f);
        } else if (idx < 4096 + 16384) {
            int i = idx - 4096; int j = i >> 7, k = i & 127;
            WT1[i] = f2bf(W1[k * HID + j]);
        } else if (idx < 4096 + 32768) {
            int i = idx - 4096 - 16384; int j = i >> 7, k = i & 127;
            WT2[i] = f2bf(W2[k * HID + j]);
        } else if (idx < 4096 + 49152) {
            int i = idx - 4096 - 32768; int j = i >> 7, k = i & 127;
            WTf[i] = f2bf(Wf[k * HID + j]);
        }
    }
}

// ---------------------------------------------------------------------------
// CSR build: histogram(tgt) -> exclusive scan -> scatter edge ids
// ---------------------------------------------------------------------------
__global__ __launch_bounds__(256) void hist_kernel(const int* __restrict__ pe_idx,
                                                   int* __restrict__ cnt) {
    int e4 = blockIdx.x * 256 + threadIdx.x;
    if (e4 < EE / 4) {
        int4 t = *(const int4*)&pe_idx[e4 * 4];
        atomicAdd(&cnt[t.x], 1);
        atomicAdd(&cnt[t.y], 1);
        atomicAdd(&cnt[t.z], 1);
        atomicAdd(&cnt[t.w], 1);
    }
}

__global__ __launch_bounds__(1024) void scan_kernel(const int* __restrict__ cnt,
                                                    int* __restrict__ woff) {
    __shared__ int s_w[16];
    int tid = threadIdx.x;
    const int chunk = 52;            // 13 int4 per thread; 1024*52 covers 50000
    int base = tid * chunk;
    int end = base + chunk; if (end > NN) end = NN;
    int s = 0;
    if (base + chunk <= NN) {
#pragma unroll
        for (int i = 0; i < 13; i++) {
            int4 v4 = *(const int4*)&cnt[base + i * 4];
            s += v4.x + v4.y + v4.z + v4.w;
        }
    } else {
        for (int i = base; i < end; i++) s += cnt[i];
    }
    int v = s;
    int lane = tid & 63, wid = tid >> 6;
#pragma unroll
    for (int d = 1; d < 64; d <<= 1) {
        int u = __shfl_up(v, d, 64);
        if (lane >= d) v += u;
    }
    if (lane == 63) s_w[wid] = v;
    __syncthreads();
    if (tid < 16) {
        int wv = s_w[tid];
#pragma unroll
        for (int d = 1; d < 16; d <<= 1) {
            int u = __shfl_up(wv, d, 64);
            if (tid >= d) wv += u;
        }
        s_w[tid] = wv;
    }
    __syncthreads();
    int exc = v - s + (wid ? s_w[wid - 1] : 0);
    int run = exc;
    for (int i = base; i < end; i++) { woff[i] = run; run += cnt[i]; }
}

__global__ __launch_bounds__(256) void scatter_kernel(const int* __restrict__ pe_idx,
                                                      int* __restrict__ woff,
                                                      int* __restrict__ perm) {
    int e4 = blockIdx.x * 256 + threadIdx.x;
    if (e4 < EE / 4) {
        int4 t = *(const int4*)&pe_idx[e4 * 4];
        int e = e4 * 4;
        perm[atomicAdd(&woff[t.x], 1)] = e + 0;
        perm[atomicAdd(&woff[t.y], 1)] = e + 1;
        perm[atomicAdd(&woff[t.z], 1)] = e + 2;
        perm[atomicAdd(&woff[t.w], 1)] = e + 3;
    }
}

// ---------------------------------------------------------------------------
// Fused edge MLP (MFMA) + gather-multiply + CSR-sorted segment reduction.
// v6 = R1 structure (best known) + x0 packed bf16 (-16 VGPR), merged top
// barrier, s_setprio around MFMA. NO live-across-GEMM prefetch (R4 spilled).
// ---------------------------------------------------------------------------
__global__ __launch_bounds__(512, 4) void edge_kernel(
    const float* __restrict__ pe_val, const int* __restrict__ pe_idx,
    const int* __restrict__ perm, const unsigned short* __restrict__ xhb,
    const unsigned short* __restrict__ WT_in, const unsigned short* __restrict__ WT1,
    const unsigned short* __restrict__ WT2, const unsigned short* __restrict__ WTf,
    const float* __restrict__ b_in, const float* __restrict__ b1,
    const float* __restrict__ b2, const float* __restrict__ bfin,
    float* __restrict__ wV) {
    __shared__ __align__(16) unsigned short s_act[EBLK][AKS];   // 34.8 KB
    __shared__ __align__(16) unsigned short s_W[HID][AKS];      // 34.8 KB
    __shared__ int s_tgt[EBLK], s_src[EBLK];
    float* s_msg = (float*)&s_W[0][0];   // reused after GEMM4 (64*128 f32 = 32 KB)

    const int tid = threadIdx.x;
    const int lane = tid & 63;
    const int w = tid >> 6;          // wave 0..7
    const int cg = w & 3;            // channel group (32 ch)
    const int eh = w >> 2;           // edge half (64 edges)
    const int ebase = eh * 64;
    const int l15 = lane & 15;
    const int quad = lane >> 4;
    const long b0 = (long)blockIdx.x * EBLK;

    if (tid < EBLK) {
        int eid = perm[b0 + tid];
        s_tgt[tid] = pe_idx[eid];
        s_src[tid] = pe_idx[EE + eid];
    }
    // stage W1 (used by GEMM2) -- disjoint LDS from pe staging, one barrier
#pragma unroll
    for (int i = 0; i < 4; i++) {
        int idx = tid + i * 512; int r = idx >> 4, seg = idx & 15;
        *(uint4*)&s_W[r][seg * 8] = *(const uint4*)&WT1[r * HID + seg * 8];
    }
    // stage pe (bf16 pairs) into act cols 0..31 (24..31 zero); perm read
    // redundantly (16 threads/edge, same address -> L1/L2 broadcast)
#pragma unroll
    for (int i = 0; i < 4; i++) {
        int idx = tid + i * 512; int e = idx >> 4, k2 = idx & 15;
        float2 v = make_float2(0.f, 0.f);
        if (k2 < 12) {
            int eid = perm[b0 + e];
            v = *(const float2*)&pe_val[(size_t)eid * PED + k2 * 2];
        }
        *(unsigned int*)&s_act[e][k2 * 2] = pkbf2(v.x, v.y);
    }
    __syncthreads();                                   // barrier A

    f32x4 C[2][4];
    uint2 x0pk[2][4];                // x0 saved as packed bf16 (16 regs)

    // ---- GEMM1: x0 = pe @ W_in + b_in  (K=32, bias in C-init) ----
    {
        float4 ba = *(const float4*)&b_in[(2 * cg + 0) * 16 + quad * 4];
        float4 bb = *(const float4*)&b_in[(2 * cg + 1) * 16 + quad * 4];
        f32x4 ci0 = {ba.x, ba.y, ba.z, ba.w};
        f32x4 ci1 = {bb.x, bb.y, bb.z, bb.w};
        bf16x8 a0 = *(const bf16x8*)&WT_in[((2 * cg + 0) * 16 + l15) * 32 + quad * 8];
        bf16x8 a1 = *(const bf16x8*)&WT_in[((2 * cg + 1) * 16 + l15) * 32 + quad * 8];
        __builtin_amdgcn_s_setprio(1);
#pragma unroll
        for (int u = 0; u < 4; u++) {
            bf16x8 bfr = *(const bf16x8*)&s_act[ebase + u * 16 + l15][quad * 8];
            C[0][u] = __builtin_amdgcn_mfma_f32_16x16x32_bf16(a0, bfr, ci0, 0, 0, 0);
            C[1][u] = __builtin_amdgcn_mfma_f32_16x16x32_bf16(a1, bfr, ci1, 0, 0, 0);
        }
        __builtin_amdgcn_s_setprio(0);
    }
    __syncthreads();                                   // barrier B (act reads done)
    // epi1: save x0 packed, gelu -> act
#pragma unroll
    for (int t = 0; t < 2; t++) {
        int ch0 = (2 * cg + t) * 16 + quad * 4;
#pragma unroll
        for (int u = 0; u < 4; u++) {
            int e = ebase + u * 16 + l15;
            f32x4 c = C[t][u];
            x0pk[t][u].x = pkbf2(c[0], c[1]);
            x0pk[t][u].y = pkbf2(c[2], c[3]);
            uint2 p;
            p.x = pkbf2(gelu_fast(c[0]), gelu_fast(c[1]));
            p.y = pkbf2(gelu_fast(c[2]), gelu_fast(c[3]));
            *(uint2*)&s_act[e][ch0] = p;
        }
    }
    __syncthreads();                                   // barrier C

#define GEMM128(BIAS)                                                          \
    {                                                                          \
        float4 ba_ = *(const float4*)&(BIAS)[(2 * cg + 0) * 16 + quad * 4];    \
        float4 bb_ = *(const float4*)&(BIAS)[(2 * cg + 1) * 16 + quad * 4];    \
        f32x4 ci0 = {ba_.x, ba_.y, ba_.z, ba_.w};                              \
        f32x4 ci1 = {bb_.x, bb_.y, bb_.z, bb_.w};                              \
        _Pragma("unroll") for (int u = 0; u < 4; u++) {                        \
            C[0][u] = ci0; C[1][u] = ci1;                                      \
        }                                                                      \
        __builtin_amdgcn_s_setprio(1);                                         \
        _Pragma("unroll") for (int ks = 0; ks < 4; ks++) {                     \
            bf16x8 a0 = *(const bf16x8*)&s_W[(2 * cg + 0) * 16 + l15]          \
                                            [ks * 32 + quad * 8];              \
            bf16x8 a1 = *(const bf16x8*)&s_W[(2 * cg + 1) * 16 + l15]          \
                                            [ks * 32 + quad * 8];              \
            _Pragma("unroll") for (int u = 0; u < 4; u++) {                    \
                bf16x8 bfr = *(const bf16x8*)&s_act[ebase + u * 16 + l15]      \
                                                   [ks * 32 + quad * 8];       \
                C[0][u] = __builtin_amdgcn_mfma_f32_16x16x32_bf16(a0, bfr,     \
                                                                  C[0][u], 0, 0, 0); \
                C[1][u] = __builtin_amdgcn_mfma_f32_16x16x32_bf16(a1, bfr,     \
                                                                  C[1][u], 0, 0, 0); \
            }                                                                  \
        }                                                                      \
        __builtin_amdgcn_s_setprio(0);                                         \
    }

#define STAGE_W(WT)                                                            \
    _Pragma("unroll") for (int i = 0; i < 4; i++) {                            \
        int idx = tid + i * 512; int r = idx >> 4, seg = idx & 15;             \
        *(uint4*)&s_W[r][seg * 8] = *(const uint4*)&(WT)[r * HID + seg * 8];   \
    }

    // ---- GEMM2: h1 = g(x0) @ W1 + b1 ; gelu -> act ; stage W2 ----
    GEMM128(b1);
    __syncthreads();                                   // barrier D
#pragma unroll
    for (int t = 0; t < 2; t++) {
        int ch0 = (2 * cg + t) * 16 + quad * 4;
#pragma unroll
        for (int u = 0; u < 4; u++) {
            int e = ebase + u * 16 + l15;
            f32x4 c = C[t][u];
            uint2 p;
            p.x = pkbf2(gelu_fast(c[0]), gelu_fast(c[1]));
            p.y = pkbf2(gelu_fast(c[2]), gelu_fast(c[3]));
            *(uint2*)&s_act[e][ch0] = p;
        }
    }
    STAGE_W(WT2);
    __syncthreads();                                   // barrier E

    // ---- GEMM3: h2 = g(h1) @ W2 + b2 ; x0' = h2 + x0 -> act ; stage Wf ----
    GEMM128(b2);
    __syncthreads();                                   // barrier F
#pragma unroll
    for (int t = 0; t < 2; t++) {
        int ch0 = (2 * cg + t) * 16 + quad * 4;
#pragma unroll
        for (int u = 0; u < 4; u++) {
            int e = ebase + u * 16 + l15;
            f32x4 c = C[t][u];
            uint2 p;
            p.x = pkbf2(c[0] + bflo(x0pk[t][u].x), c[1] + bfhi(x0pk[t][u].x));
            p.y = pkbf2(c[2] + bflo(x0pk[t][u].y), c[3] + bfhi(x0pk[t][u].y));
            *(uint2*)&s_act[e][ch0] = p;
        }
    }
    STAGE_W(WTf);
    __syncthreads();                                   // barrier G

    // ---- GEMM4: score = x0' @ W_fin + b_fin -> act (bf16) ----
    GEMM128(bfin);
    // prefetch pass-0 xh gathers (needs only s_src; hides under epi4+sync)
    uint2 xva[4];
#pragma unroll
    for (int i = 0; i < 4; i++) {
        int idx = tid + i * 512; int e = idx >> 5, c4 = idx & 31;
        xva[i] = ((const uint2*)&xhb[(size_t)s_src[e] * HID])[c4];
    }
    __syncthreads();                                   // barrier H (GEMM4 reads done)
#pragma unroll
    for (int t = 0; t < 2; t++) {
        int ch0 = (2 * cg + t) * 16 + quad * 4;
#pragma unroll
        for (int u = 0; u < 4; u++) {
            int e = ebase + u * 16 + l15;
            f32x4 c = C[t][u];
            uint2 p;
            p.x = pkbf2(c[0], c[1]);
            p.y = pkbf2(c[2], c[3]);
            *(uint2*)&s_act[e][ch0] = p;
        }
    }
    __syncthreads();                                   // barrier I (scores ready)

    // ---- Pass 0 Phase A: msg = xh[src]*score for edges [0,64) -> s_msg ----
#pragma unroll
    for (int i = 0; i < 4; i++) {
        int idx = tid + i * 512;          // [0, 2048) = 64 edges x 32 chunks
        int e = idx >> 5, c4 = idx & 31;
        uint2 xv = xva[i];
        uint2 sv = *(const uint2*)&s_act[e][c4 * 4];
        float4 m;
        m.x = bflo(xv.x) * bflo(sv.x);
        m.y = bfhi(xv.x) * bfhi(sv.x);
        m.z = bflo(xv.y) * bflo(sv.y);
        m.w = bfhi(xv.y) * bfhi(sv.y);
        *(float4*)&s_msg[e * HID + c4 * 4] = m;
    }
    // prefetch pass-1 xh gathers; latency hides under pass-0 walk
    uint2 xvb[4];
#pragma unroll
    for (int i = 0; i < 4; i++) {
        int idx = tid + (4 + i) * 512; int e = idx >> 5, c4 = idx & 31;
        xvb[i] = ((const uint2*)&xhb[(size_t)s_src[e] * HID])[c4];
    }
    __syncthreads();

    // ---- Pass 0 Phase B: per-channel segment walk, edges [0,64) ----
    if (tid < 256) {
        const int h = tid >> 7;
        const int c = tid & 127;
        const int e0 = h * 32;
        float acc = 0.f;
        int prev = s_tgt[e0];
        bool firstseg = true;
        for (int e = e0; e < e0 + 32; e++) {
            int tg = s_tgt[e];
            if (tg != prev) {
                if (firstseg) atomicAdd(&wV[(size_t)prev * HID + c], acc);
                else          wV[(size_t)prev * HID + c] = acc;
                firstseg = false;
                acc = 0.f;
                prev = tg;
            }
            acc += s_msg[e * HID + c];
        }
        atomicAdd(&wV[(size_t)prev * HID + c], acc);
    }
    __syncthreads();   // walk done before s_msg overwritten

    // ---- Pass 1 Phase A: edges [64,128) ----
#pragma unroll
    for (int i = 0; i < 4; i++) {
        int idx = tid + (4 + i) * 512;    // [2048, 4096)
        int e = idx >> 5, c4 = idx & 31;  // e in [64,128)
        uint2 xv = xvb[i];
        uint2 sv = *(const uint2*)&s_act[e][c4 * 4];
        float4 m;
        m.x = bflo(xv.x) * bflo(sv.x);
        m.y = bfhi(xv.x) * bfhi(sv.x);
        m.z = bflo(xv.y) * bflo(sv.y);
        m.w = bfhi(xv.y) * bfhi(sv.y);
        *(float4*)&s_msg[(e - 64) * HID + c4 * 4] = m;
    }
    __syncthreads();

    // ---- Pass 1 Phase B: edges [64,128) ----
    if (tid < 256) {
        const int h = tid >> 7;
        const int c = tid & 127;
        const int e0 = 64 + h * 32;
        float acc = 0.f;
        int prev = s_tgt[e0];
        bool firstseg = true;
        for (int e = e0; e < e0 + 32; e++) {
            int tg = s_tgt[e];
            if (tg != prev) {
                if (firstseg) atomicAdd(&wV[(size_t)prev * HID + c], acc);
                else          wV[(size_t)prev * HID + c] = acc;
                firstseg = false;
                acc = 0.f;
                prev = tg;
            }
            acc += s_msg[(e - 64) * HID + c];
        }
        atomicAdd(&wV[(size_t)prev * HID + c], acc);
    }
#undef GEMM128
#undef STAGE_W
}

// ---------------------------------------------------------------------------
// out = (wV / max(deg,1) + head_bias) @ W_out + b_out
// v2: 64 nodes/block, thread = 4 nodes x 4 ch; W_out + head_bias LDS-staged.
// ---------------------------------------------------------------------------
__global__ __launch_bounds__(256) void out_kernel(
    const float* __restrict__ wV, const int* __restrict__ cnt,
    const float* __restrict__ head_bias, const float* __restrict__ W_out,
    const float* __restrict__ b_out, float* __restrict__ out) {
    __shared__ float s_Wo[HID * OUTD];     // 32 KB
    __shared__ float s_hb[HID];
    int tid = threadIdx.x;
#pragma unroll
    for (int i = 0; i < 8; i++) {
        int idx = tid + i * 256;           // 2048 float4
        *(float4*)&s_Wo[idx * 4] = *(const float4*)&W_out[idx * 4];
    }
    if (tid < 32) *(float4*)&s_hb[tid * 4] = *(const float4*)&head_bias[tid * 4];
    __syncthreads();

    const int g = tid >> 4;                // node group 0..15
    const int q = tid & 15;                // out-channel quad: ch = q*4
    const int nb = blockIdx.x * ONB + g * 4;
    float4 bb = *(const float4*)&b_out[q * 4];
    f32x4 acc[4];
    float inv[4];
    int nc[4];
#pragma unroll
    for (int j = 0; j < 4; j++) {
        acc[j] = (f32x4){bb.x, bb.y, bb.z, bb.w};
        int n = nb + j;
        nc[j] = n < NN ? n : NN - 1;
        inv[j] = 1.0f / fmaxf((float)cnt[nc[j]], 1.0f);
    }
#pragma unroll
    for (int k4 = 0; k4 < 32; k4++) {
        float4 wrv[4];
#pragma unroll
        for (int j = 0; j < 4; j++)
            wrv[j] = *(const float4*)&wV[(size_t)nc[j] * HID + k4 * 4];
#pragma unroll
        for (int kk = 0; kk < 4; kk++) {
            int k = k4 * 4 + kk;
            float4 w4 = *(const float4*)&s_Wo[k * OUTD + q * 4];
            float hbk = s_hb[k];
#pragma unroll
            for (int j = 0; j < 4; j++) {
                float hv = __builtin_fmaf(((const float*)&wrv[j])[kk], inv[j], hbk);
                acc[j][0] += hv * w4.x; acc[j][1] += hv * w4.y;
                acc[j][2] += hv * w4.z; acc[j][3] += hv * w4.w;
            }
        }
    }
#pragma unroll
    for (int j = 0; j < 4; j++) {
        int n = nb + j;
        if (n < NN) {
            float4 o = {acc[j][0], acc[j][1], acc[j][2], acc[j][3]};
            *(float4*)&out[(size_t)n * OUTD + q * 4] = o;
        }
    }
}

extern "C" void kernel_launch(void* const* d_in, const int* in_sizes, int n_in,
                              void* d_out, int out_size, void* d_ws, size_t ws_size,
                              hipStream_t stream) {
    const float* x      = (const float*)d_in[0];
    const int*   pe_idx = (const int*)d_in[1];
    const float* pe_val = (const float*)d_in[2];
    const float* W_in   = (const float*)d_in[3];
    const float* b_in   = (const float*)d_in[4];
    const float* W1     = (const float*)d_in[5];
    const float* b1     = (const float*)d_in[6];
    const float* W2     = (const float*)d_in[7];
    const float* b2     = (const float*)d_in[8];
    const float* Wf     = (const float*)d_in[9];
    const float* bfin   = (const float*)d_in[10];
    const float* W_x    = (const float*)d_in[11];
    const float* b_x    = (const float*)d_in[12];
    const float* hb     = (const float*)d_in[13];
    const float* W_out  = (const float*)d_in[14];
    const float* b_out  = (const float*)d_in[15];
    float* out = (float*)d_out;

    // ws layout:
    // wV f32 [N*128] | cnt i32 [N] | woff i32 [N] | perm i32 [E] |
    // WT_in u16 [4096] | WT1/WT2/WTf u16 [16384 each] | xhb u16 [N*128]
    float* wV   = (float*)d_ws;
    int*   cnt  = (int*)(wV + (size_t)NN * HID);
    int*   woff = cnt + NN;
    int*   perm = woff + NN;
    unsigned short* WT_in = (unsigned short*)(perm + EE);
    unsigned short* WT1   = WT_in + 128 * 32;
    unsigned short* WT2   = WT1 + 128 * 128;
    unsigned short* WTf   = WT2 + 128 * 128;
    unsigned short* xhb   = WTf + 128 * 128;

    pre_kernel<<<XHB + 208, 256, 0, stream>>>(x, W_x, b_x, xhb,
                                              W_in, W1, W2, Wf,
                                              WT_in, WT1, WT2, WTf, wV, cnt);
    hist_kernel<<<(EE / 4 + 255) / 256, 256, 0, stream>>>(pe_idx, cnt);
    scan_kernel<<<1, 1024, 0, stream>>>(cnt, woff);
    scatter_kernel<<<(EE / 4 + 255) / 256, 256, 0, stream>>>(pe_idx, woff, perm);

    edge_kernel<<<EE / EBLK, 512, 0, stream>>>(pe_val, pe_idx, perm, xhb,
                                               WT_in, WT1, WT2, WTf,
                                               b_in, b1, b2, bfin, wV);

    out_kernel<<<(NN + ONB - 1) / ONB, 256, 0, stream>>>(wV, cnt, hb, W_out,
                                                         b_out, out);
}

// Round 6
// 592.901 us; speedup vs baseline: 1.9355x; 1.9355x over previous
//
#include <hip/hip_runtime.h>
#include <hip/hip_bf16.h>
#include <math.h>

#define NN 50000
#define EE 800000
#define HID 128
#define PED 24
#define IND 64
#define OUTD 64
#define EBLK 128         // edges per edge-kernel block
#define AKS 136          // act/W LDS k-stride in bf16 (272 B: 16B-aligned, bank-spread)

typedef short bf16x8 __attribute__((ext_vector_type(8)));
typedef float f32x4 __attribute__((ext_vector_type(4)));

// GELU tanh-form via sigmoid: x * sigmoid(1.5957691x + 0.07135481x^3).
// max |err| vs exact-erf GELU ~4e-4 (below bf16 noise); 6 VALU + 2 trans.
__device__ __forceinline__ float gelu_fast(float x) {
    float x2 = x * x;
    float t = __builtin_fmaf(x2, -0.07135481627f, -1.5957691216f);
    float e = __expf(x * t);
    return x * __builtin_amdgcn_rcpf(1.0f + e);
}
__device__ __forceinline__ unsigned short f2bf(float f) {
    unsigned int u = __float_as_uint(f);
    u = (u + 0x7fffu + ((u >> 16) & 1u)) >> 16;   // RNE
    return (unsigned short)u;
}
__device__ __forceinline__ unsigned int pkbf2(float a, float b) {
    __hip_bfloat162 h = __float22bfloat162_rn(make_float2(a, b));  // a -> low
    return *reinterpret_cast<unsigned int*>(&h);
}
__device__ __forceinline__ float bflo(unsigned int u) {
    return __uint_as_float(u << 16);
}
__device__ __forceinline__ float bfhi(unsigned int u) {
    return __uint_as_float(u & 0xffff0000u);
}

// ---------------------------------------------------------------------------
// Fused pre-pass (R1 known-good):
//   blocks [0, 6250):    xh_bf16 = bf16(x @ W_x + b_x) AND zero wV
//   blocks [6250, 6458): weight transposes WT_* AND zero cnt
// ---------------------------------------------------------------------------
__global__ __launch_bounds__(256) void pre_kernel(
    const float* __restrict__ x, const float* __restrict__ W_x,
    const float* __restrict__ b_x, unsigned short* __restrict__ xhb,
    const float* __restrict__ W_in, const float* __restrict__ W1,
    const float* __restrict__ W2, const float* __restrict__ Wf,
    unsigned short* __restrict__ WT_in, unsigned short* __restrict__ WT1,
    unsigned short* __restrict__ WT2, unsigned short* __restrict__ WTf,
    float* __restrict__ wV, int* __restrict__ cnt) {
    int bx = blockIdx.x;
    if (bx < 6250) {
        int gid = bx * 256 + threadIdx.x;
        int n = gid >> 5;               // 6250*256/32 = 50000 exactly
        int q = gid & 31;
        *(float4*)&wV[(size_t)n * HID + q * 4] = make_float4(0.f, 0.f, 0.f, 0.f);
        const float* xr = x + (size_t)n * IND;
        float4 acc = *(const float4*)&b_x[q * 4];
#pragma unroll 8
        for (int k = 0; k < IND; k++) {
            float xk = xr[k];
            float4 w = *(const float4*)&W_x[k * HID + q * 4];
            acc.x += xk * w.x; acc.y += xk * w.y;
            acc.z += xk * w.z; acc.w += xk * w.w;
        }
        uint2 p;
        p.x = pkbf2(acc.x, acc.y);
        p.y = pkbf2(acc.z, acc.w);
        ((uint2*)&xhb[(size_t)n * HID])[q] = p;
    } else {
        int idx = (bx - 6250) * 256 + threadIdx.x;   // [0, 53248)
        if (idx < NN) cnt[idx] = 0;
        if (idx < 4096) {                       // WT_in [128][32], k>=24 zero-pad
            int j = idx >> 5, k = idx & 31;
            WT_in[idx] = f2bf(k < PED ? W_in[k * HID + j] : 0.f);
        } else if (idx < 4096 + 16384) {
            int i = idx - 4096; int j = i >> 7, k = i & 127;
            WT1[i] = f2bf(W1[k * HID + j]);
        } else if (idx < 4096 + 32768) {
            int i = idx - 4096 - 16384; int j = i >> 7, k = i & 127;
            WT2[i] = f2bf(W2[k * HID + j]);
        } else if (idx < 4096 + 49152) {
            int i = idx - 4096 - 32768; int j = i >> 7, k = i & 127;
            WTf[i] = f2bf(Wf[k * HID + j]);
        }
    }
}

// ---------------------------------------------------------------------------
// CSR build: histogram(tgt) -> exclusive scan -> scatter edge ids
// ---------------------------------------------------------------------------
__global__ __launch_bounds__(256) void hist_kernel(const int* __restrict__ pe_idx,
                                                   int* __restrict__ cnt) {
    int e4 = blockIdx.x * 256 + threadIdx.x;
    if (e4 < EE / 4) {
        int4 t = *(const int4*)&pe_idx[e4 * 4];
        atomicAdd(&cnt[t.x], 1);
        atomicAdd(&cnt[t.y], 1);
        atomicAdd(&cnt[t.z], 1);
        atomicAdd(&cnt[t.w], 1);
    }
}

__global__ __launch_bounds__(1024) void scan_kernel(const int* __restrict__ cnt,
                                                    int* __restrict__ woff) {
    __shared__ int s_w[16];
    int tid = threadIdx.x;
    const int chunk = 52;            // 13 int4 per thread; 1024*52 covers 50000
    int base = tid * chunk;
    int end = base + chunk; if (end > NN) end = NN;
    int s = 0;
    if (base + chunk <= NN) {
#pragma unroll
        for (int i = 0; i < 13; i++) {
            int4 v4 = *(const int4*)&cnt[base + i * 4];
            s += v4.x + v4.y + v4.z + v4.w;
        }
    } else {
        for (int i = base; i < end; i++) s += cnt[i];
    }
    int v = s;
    int lane = tid & 63, wid = tid >> 6;
#pragma unroll
    for (int d = 1; d < 64; d <<= 1) {
        int u = __shfl_up(v, d, 64);
        if (lane >= d) v += u;
    }
    if (lane == 63) s_w[wid] = v;
    __syncthreads();
    if (tid < 16) {
        int wv = s_w[tid];
#pragma unroll
        for (int d = 1; d < 16; d <<= 1) {
            int u = __shfl_up(wv, d, 64);
            if (tid >= d) wv += u;
        }
        s_w[tid] = wv;
    }
    __syncthreads();
    int exc = v - s + (wid ? s_w[wid - 1] : 0);
    int run = exc;
    for (int i = base; i < end; i++) { woff[i] = run; run += cnt[i]; }
}

__global__ __launch_bounds__(256) void scatter_kernel(const int* __restrict__ pe_idx,
                                                      int* __restrict__ woff,
                                                      int* __restrict__ perm) {
    int e4 = blockIdx.x * 256 + threadIdx.x;
    if (e4 < EE / 4) {
        int4 t = *(const int4*)&pe_idx[e4 * 4];
        int e = e4 * 4;
        perm[atomicAdd(&woff[t.x], 1)] = e + 0;
        perm[atomicAdd(&woff[t.y], 1)] = e + 1;
        perm[atomicAdd(&woff[t.z], 1)] = e + 2;
        perm[atomicAdd(&woff[t.w], 1)] = e + 3;
    }
}

// ---------------------------------------------------------------------------
// Fused edge MLP (MFMA) + gather-multiply + CSR-sorted segment reduction.
// v7 = R1 structure + x0 packed bf16 + setprio + merged top barrier, PLUS:
//  - s_pe side buffer (8 KB) for GEMM1 B-operand -> epi1 has no WAR on act
//    -> barrier B deleted (LDS 78.8 KB, still 2 blocks/CU).
//  - single-pass wave-local walk: wave w owns edges [16w,16w+16), lane =
//    channel pair (u32 = 2 bf16). xh gathers prefetched after GEMM4 MFMAs
//    (R1's proven slot). No s_msg, no Phase A, 3 fewer barriers, all 512
//    threads active, wave-uniform segment branch (zero divergence).
// Barriers: 8 (was 11).
// ---------------------------------------------------------------------------
__global__ __launch_bounds__(512, 4) void edge_kernel(
    const float* __restrict__ pe_val, const int* __restrict__ pe_idx,
    const int* __restrict__ perm, const unsigned short* __restrict__ xhb,
    const unsigned short* __restrict__ WT_in, const unsigned short* __restrict__ WT1,
    const unsigned short* __restrict__ WT2, const unsigned short* __restrict__ WTf,
    const float* __restrict__ b_in, const float* __restrict__ b1,
    const float* __restrict__ b2, const float* __restrict__ bfin,
    float* __restrict__ wV) {
    __shared__ __align__(16) unsigned short s_act[EBLK][AKS];   // 34.8 KB
    __shared__ __align__(16) unsigned short s_W[HID][AKS];      // 34.8 KB
    __shared__ __align__(16) unsigned short s_pe[EBLK][32];     // 8 KB
    __shared__ int s_tgt[EBLK], s_src[EBLK];

    const int tid = threadIdx.x;
    const int lane = tid & 63;
    const int w = tid >> 6;          // wave 0..7
    const int cg = w & 3;            // channel group (32 ch)
    const int eh = w >> 2;           // edge half (64 edges)
    const int ebase = eh * 64;
    const int l15 = lane & 15;
    const int quad = lane >> 4;
    const long b0 = (long)blockIdx.x * EBLK;

    if (tid < EBLK) {
        int eid = perm[b0 + tid];
        s_tgt[tid] = pe_idx[eid];
        s_src[tid] = pe_idx[EE + eid];
    }
    // stage W1 (used by GEMM2) -- disjoint LDS from pe staging, one barrier
#pragma unroll
    for (int i = 0; i < 4; i++) {
        int idx = tid + i * 512; int r = idx >> 4, seg = idx & 15;
        *(uint4*)&s_W[r][seg * 8] = *(const uint4*)&WT1[r * HID + seg * 8];
    }
    // stage pe (bf16 pairs) into s_pe cols 0..31 (24..31 zero); perm read
    // redundantly (16 threads/edge, same address -> L1/L2 broadcast)
#pragma unroll
    for (int i = 0; i < 4; i++) {
        int idx = tid + i * 512; int e = idx >> 4, k2 = idx & 15;
        float2 v = make_float2(0.f, 0.f);
        if (k2 < 12) {
            int eid = perm[b0 + e];
            v = *(const float2*)&pe_val[(size_t)eid * PED + k2 * 2];
        }
        *(unsigned int*)&s_pe[e][k2 * 2] = pkbf2(v.x, v.y);
    }
    __syncthreads();                                   // barrier A

    f32x4 C[2][4];
    uint2 x0pk[2][4];                // x0 saved as packed bf16 (16 regs)

    // ---- GEMM1: x0 = pe @ W_in + b_in  (K=32, B from s_pe, bias in C-init)
    {
        float4 ba = *(const float4*)&b_in[(2 * cg + 0) * 16 + quad * 4];
        float4 bb = *(const float4*)&b_in[(2 * cg + 1) * 16 + quad * 4];
        f32x4 ci0 = {ba.x, ba.y, ba.z, ba.w};
        f32x4 ci1 = {bb.x, bb.y, bb.z, bb.w};
        bf16x8 a0 = *(const bf16x8*)&WT_in[((2 * cg + 0) * 16 + l15) * 32 + quad * 8];
        bf16x8 a1 = *(const bf16x8*)&WT_in[((2 * cg + 1) * 16 + l15) * 32 + quad * 8];
        __builtin_amdgcn_s_setprio(1);
#pragma unroll
        for (int u = 0; u < 4; u++) {
            bf16x8 bfr = *(const bf16x8*)&s_pe[ebase + u * 16 + l15][quad * 8];
            C[0][u] = __builtin_amdgcn_mfma_f32_16x16x32_bf16(a0, bfr, ci0, 0, 0, 0);
            C[1][u] = __builtin_amdgcn_mfma_f32_16x16x32_bf16(a1, bfr, ci1, 0, 0, 0);
        }
        __builtin_amdgcn_s_setprio(0);
    }
    // epi1: save x0 packed, gelu -> act (act not yet read by anyone: no WAR)
#pragma unroll
    for (int t = 0; t < 2; t++) {
        int ch0 = (2 * cg + t) * 16 + quad * 4;
#pragma unroll
        for (int u = 0; u < 4; u++) {
            int e = ebase + u * 16 + l15;
            f32x4 c = C[t][u];
            x0pk[t][u].x = pkbf2(c[0], c[1]);
            x0pk[t][u].y = pkbf2(c[2], c[3]);
            uint2 p;
            p.x = pkbf2(gelu_fast(c[0]), gelu_fast(c[1]));
            p.y = pkbf2(gelu_fast(c[2]), gelu_fast(c[3]));
            *(uint2*)&s_act[e][ch0] = p;
        }
    }
    __syncthreads();                                   // barrier C (act ready)

#define GEMM128(BIAS)                                                          \
    {                                                                          \
        float4 ba_ = *(const float4*)&(BIAS)[(2 * cg + 0) * 16 + quad * 4];    \
        float4 bb_ = *(const float4*)&(BIAS)[(2 * cg + 1) * 16 + quad * 4];    \
        f32x4 ci0 = {ba_.x, ba_.y, ba_.z, ba_.w};                              \
        f32x4 ci1 = {bb_.x, bb_.y, bb_.z, bb_.w};                              \
        _Pragma("unroll") for (int u = 0; u < 4; u++) {                        \
            C[0][u] = ci0; C[1][u] = ci1;                                      \
        }                                                                      \
        __builtin_amdgcn_s_setprio(1);                                         \
        _Pragma("unroll") for (int ks = 0; ks < 4; ks++) {                     \
            bf16x8 a0 = *(const bf16x8*)&s_W[(2 * cg + 0) * 16 + l15]          \
                                            [ks * 32 + quad * 8];              \
            bf16x8 a1 = *(const bf16x8*)&s_W[(2 * cg + 1) * 16 + l15]          \
                                            [ks * 32 + quad * 8];              \
            _Pragma("unroll") for (int u = 0; u < 4; u++) {                    \
                bf16x8 bfr = *(const bf16x8*)&s_act[ebase + u * 16 + l15]      \
                                                   [ks * 32 + quad * 8];       \
                C[0][u] = __builtin_amdgcn_mfma_f32_16x16x32_bf16(a0, bfr,     \
                                                                  C[0][u], 0, 0, 0); \
                C[1][u] = __builtin_amdgcn_mfma_f32_16x16x32_bf16(a1, bfr,     \
                                                                  C[1][u], 0, 0, 0); \
            }                                                                  \
        }                                                                      \
        __builtin_amdgcn_s_setprio(0);                                         \
    }

#define STAGE_W(WT)                                                            \
    _Pragma("unroll") for (int i = 0; i < 4; i++) {                            \
        int idx = tid + i * 512; int r = idx >> 4, seg = idx & 15;             \
        *(uint4*)&s_W[r][seg * 8] = *(const uint4*)&(WT)[r * HID + seg * 8];   \
    }

    // ---- GEMM2: h1 = g(x0) @ W1 + b1 ; gelu -> act ; stage W2 ----
    GEMM128(b1);
    __syncthreads();                                   // barrier D
#pragma unroll
    for (int t = 0; t < 2; t++) {
        int ch0 = (2 * cg + t) * 16 + quad * 4;
#pragma unroll
        for (int u = 0; u < 4; u++) {
            int e = ebase + u * 16 + l15;
            f32x4 c = C[t][u];
            uint2 p;
            p.x = pkbf2(gelu_fast(c[0]), gelu_fast(c[1]));
            p.y = pkbf2(gelu_fast(c[2]), gelu_fast(c[3]));
            *(uint2*)&s_act[e][ch0] = p;
        }
    }
    STAGE_W(WT2);
    __syncthreads();                                   // barrier E

    // ---- GEMM3: h2 = g(h1) @ W2 + b2 ; x0' = h2 + x0 -> act ; stage Wf ----
    GEMM128(b2);
    __syncthreads();                                   // barrier F
#pragma unroll
    for (int t = 0; t < 2; t++) {
        int ch0 = (2 * cg + t) * 16 + quad * 4;
#pragma unroll
        for (int u = 0; u < 4; u++) {
            int e = ebase + u * 16 + l15;
            f32x4 c = C[t][u];
            uint2 p;
            p.x = pkbf2(c[0] + bflo(x0pk[t][u].x), c[1] + bfhi(x0pk[t][u].x));
            p.y = pkbf2(c[2] + bflo(x0pk[t][u].y), c[3] + bfhi(x0pk[t][u].y));
            *(uint2*)&s_act[e][ch0] = p;
        }
    }
    STAGE_W(WTf);
    __syncthreads();                                   // barrier G

    // ---- GEMM4: score = x0' @ W_fin + b_fin -> act (bf16) ----
    GEMM128(bfin);
    // prefetch xh gathers for the walk: wave w owns edges [16w, 16w+16),
    // lane = channel pair. 64 lanes x 4B = 256B/edge, coalesced. Issued
    // after GEMM4's MFMAs so latency hides under epi4 + barriers H,I.
    const int e0 = w * 16;
    unsigned int xv[16];
#pragma unroll
    for (int j = 0; j < 16; j++) {
        xv[j] = *(const unsigned int*)&xhb[(size_t)s_src[e0 + j] * HID + lane * 2];
    }
    __syncthreads();                                   // barrier H (GEMM4 reads done)
#pragma unroll
    for (int t = 0; t < 2; t++) {
        int ch0 = (2 * cg + t) * 16 + quad * 4;
#pragma unroll
        for (int u = 0; u < 4; u++) {
            int e = ebase + u * 16 + l15;
            f32x4 c = C[t][u];
            uint2 p;
            p.x = pkbf2(c[0], c[1]);
            p.y = pkbf2(c[2], c[3]);
            *(uint2*)&s_act[e][ch0] = p;
        }
    }
    __syncthreads();                                   // barrier I (scores ready)

    // ---- Single-pass wave-local segment walk ----
    // tg/prev are wave-uniform (LDS broadcast) -> uniform branch. Interior
    // segments: plain float2 store; boundary segments: 2x atomicAdd.
    {
        float a0 = 0.f, a1 = 0.f;
        int prev = s_tgt[e0];
        bool firstseg = true;
#pragma unroll
        for (int j = 0; j < 16; j++) {
            int tg = s_tgt[e0 + j];
            if (tg != prev) {
                float* wp = &wV[(size_t)prev * HID + lane * 2];
                if (firstseg) { atomicAdd(wp, a0); atomicAdd(wp + 1, a1); }
                else          { *(float2*)wp = make_float2(a0, a1); }
                firstseg = false;
                a0 = a1 = 0.f;
                prev = tg;
            }
            unsigned int sv = *(const unsigned int*)&s_act[e0 + j][lane * 2];
            unsigned int xu = xv[j];
            a0 += bflo(xu) * bflo(sv);
            a1 += bfhi(xu) * bfhi(sv);
        }
        float* wp = &wV[(size_t)prev * HID + lane * 2];
        atomicAdd(wp, a0); atomicAdd(wp + 1, a1);      // last seg may span blocks
    }
#undef GEMM128
#undef STAGE_W
}

// ---------------------------------------------------------------------------
// out = (wV / max(deg,1) + head_bias) @ W_out + b_out ; 4 outputs/thread
// (R1 known-good)
// ---------------------------------------------------------------------------
__global__ __launch_bounds__(256) void out_kernel(
    const float* __restrict__ wV, const int* __restrict__ cnt,
    const float* __restrict__ head_bias, const float* __restrict__ W_out,
    const float* __restrict__ b_out, float* __restrict__ out) {
    int gid = blockIdx.x * 256 + threadIdx.x;
    int n = gid >> 4;
    int q = gid & 15;
    if (n >= NN) return;
    float inv = 1.0f / fmaxf((float)cnt[n], 1.0f);
    const float* wr = wV + (size_t)n * HID;
    float4 acc = *(const float4*)&b_out[q * 4];
#pragma unroll 4
    for (int k = 0; k < HID; k++) {
        float hv = wr[k] * inv + head_bias[k];
        float4 wv4 = *(const float4*)&W_out[k * OUTD + q * 4];
        acc.x += hv * wv4.x; acc.y += hv * wv4.y;
        acc.z += hv * wv4.z; acc.w += hv * wv4.w;
    }
    *(float4*)&out[(size_t)n * OUTD + q * 4] = acc;
}

extern "C" void kernel_launch(void* const* d_in, const int* in_sizes, int n_in,
                              void* d_out, int out_size, void* d_ws, size_t ws_size,
                              hipStream_t stream) {
    const float* x      = (const float*)d_in[0];
    const int*   pe_idx = (const int*)d_in[1];
    const float* pe_val = (const float*)d_in[2];
    const float* W_in   = (const float*)d_in[3];
    const float* b_in   = (const float*)d_in[4];
    const float* W1     = (const float*)d_in[5];
    const float* b1     = (const float*)d_in[6];
    const float* W2     = (const float*)d_in[7];
    const float* b2     = (const float*)d_in[8];
    const float* Wf     = (const float*)d_in[9];
    const float* bfin   = (const float*)d_in[10];
    const float* W_x    = (const float*)d_in[11];
    const float* b_x    = (const float*)d_in[12];
    const float* hb     = (const float*)d_in[13];
    const float* W_out  = (const float*)d_in[14];
    const float* b_out  = (const float*)d_in[15];
    float* out = (float*)d_out;

    // ws layout:
    // wV f32 [N*128] | cnt i32 [N] | woff i32 [N] | perm i32 [E] |
    // WT_in u16 [4096] | WT1/WT2/WTf u16 [16384 each] | xhb u16 [N*128]
    float* wV   = (float*)d_ws;
    int*   cnt  = (int*)(wV + (size_t)NN * HID);
    int*   woff = cnt + NN;
    int*   perm = woff + NN;
    unsigned short* WT_in = (unsigned short*)(perm + EE);
    unsigned short* WT1   = WT_in + 128 * 32;
    unsigned short* WT2   = WT1 + 128 * 128;
    unsigned short* WTf   = WT2 + 128 * 128;
    unsigned short* xhb   = WTf + 128 * 128;

    pre_kernel<<<6250 + 208, 256, 0, stream>>>(x, W_x, b_x, xhb,
                                               W_in, W1, W2, Wf,
                                               WT_in, WT1, WT2, WTf, wV, cnt);
    hist_kernel<<<(EE / 4 + 255) / 256, 256, 0, stream>>>(pe_idx, cnt);
    scan_kernel<<<1, 1024, 0, stream>>>(cnt, woff);
    scatter_kernel<<<(EE / 4 + 255) / 256, 256, 0, stream>>>(pe_idx, woff, perm);

    edge_kernel<<<EE / EBLK, 512, 0, stream>>>(pe_val, pe_idx, perm, xhb,
                                               WT_in, WT1, WT2, WTf,
                                               b_in, b1, b2, bfin, wV);

    out_kernel<<<(NN * 16 + 255) / 256, 256, 0, stream>>>(wV, cnt, hb, W_out,
                                                          b_out, out);
}

// Round 7
// 587.110 us; speedup vs baseline: 1.9546x; 1.0099x over previous
//
#include <hip/hip_runtime.h>
#include <hip/hip_bf16.h>
#include <math.h>

#define NN 50000
#define EE 800000
#define HID 128
#define PED 24
#define IND 64
#define OUTD 64
#define EBLK 128         // edges per edge-kernel block
#define AKS 136          // act/W LDS k-stride in bf16 (272 B: 16B-aligned, bank-spread)

typedef short bf16x8 __attribute__((ext_vector_type(8)));
typedef float f32x4 __attribute__((ext_vector_type(4)));

// GELU tanh-form via sigmoid: x * sigmoid(1.5957691x + 0.07135481x^3).
// max |err| vs exact-erf GELU ~4e-4 (below bf16 noise); 6 VALU + 2 trans.
__device__ __forceinline__ float gelu_fast(float x) {
    float x2 = x * x;
    float t = __builtin_fmaf(x2, -0.07135481627f, -1.5957691216f);
    float e = __expf(x * t);
    return x * __builtin_amdgcn_rcpf(1.0f + e);
}
__device__ __forceinline__ unsigned short f2bf(float f) {
    unsigned int u = __float_as_uint(f);
    u = (u + 0x7fffu + ((u >> 16) & 1u)) >> 16;   // RNE
    return (unsigned short)u;
}
__device__ __forceinline__ unsigned int pkbf2(float a, float b) {
    __hip_bfloat162 h = __float22bfloat162_rn(make_float2(a, b));  // a -> low
    return *reinterpret_cast<unsigned int*>(&h);
}
__device__ __forceinline__ float bflo(unsigned int u) {
    return __uint_as_float(u << 16);
}
__device__ __forceinline__ float bfhi(unsigned int u) {
    return __uint_as_float(u & 0xffff0000u);
}

// ---------------------------------------------------------------------------
// Fused pre-pass:
//   blocks [0, 6250):    xh_bf16 = bf16(x @ W_x + b_x) AND zero wV
//                        (x row read as float4, R7)
//   blocks [6250, 6458): weight transposes WT_* AND zero cnt
// ---------------------------------------------------------------------------
__global__ __launch_bounds__(256) void pre_kernel(
    const float* __restrict__ x, const float* __restrict__ W_x,
    const float* __restrict__ b_x, unsigned short* __restrict__ xhb,
    const float* __restrict__ W_in, const float* __restrict__ W1,
    const float* __restrict__ W2, const float* __restrict__ Wf,
    unsigned short* __restrict__ WT_in, unsigned short* __restrict__ WT1,
    unsigned short* __restrict__ WT2, unsigned short* __restrict__ WTf,
    float* __restrict__ wV, int* __restrict__ cnt) {
    int bx = blockIdx.x;
    if (bx < 6250) {
        int gid = bx * 256 + threadIdx.x;
        int n = gid >> 5;               // 6250*256/32 = 50000 exactly
        int q = gid & 31;
        *(float4*)&wV[(size_t)n * HID + q * 4] = make_float4(0.f, 0.f, 0.f, 0.f);
        const float4* xr4 = (const float4*)(x + (size_t)n * IND);
        float4 acc = *(const float4*)&b_x[q * 4];
#pragma unroll 4
        for (int k4 = 0; k4 < 16; k4++) {
            float4 xv = xr4[k4];
            {
                float xk = xv.x;
                float4 w = *(const float4*)&W_x[(k4 * 4 + 0) * HID + q * 4];
                acc.x += xk * w.x; acc.y += xk * w.y;
                acc.z += xk * w.z; acc.w += xk * w.w;
            }
            {
                float xk = xv.y;
                float4 w = *(const float4*)&W_x[(k4 * 4 + 1) * HID + q * 4];
                acc.x += xk * w.x; acc.y += xk * w.y;
                acc.z += xk * w.z; acc.w += xk * w.w;
            }
            {
                float xk = xv.z;
                float4 w = *(const float4*)&W_x[(k4 * 4 + 2) * HID + q * 4];
                acc.x += xk * w.x; acc.y += xk * w.y;
                acc.z += xk * w.z; acc.w += xk * w.w;
            }
            {
                float xk = xv.w;
                float4 w = *(const float4*)&W_x[(k4 * 4 + 3) * HID + q * 4];
                acc.x += xk * w.x; acc.y += xk * w.y;
                acc.z += xk * w.z; acc.w += xk * w.w;
            }
        }
        uint2 p;
        p.x = pkbf2(acc.x, acc.y);
        p.y = pkbf2(acc.z, acc.w);
        ((uint2*)&xhb[(size_t)n * HID])[q] = p;
    } else {
        int idx = (bx - 6250) * 256 + threadIdx.x;   // [0, 53248)
        if (idx < NN) cnt[idx] = 0;
        if (idx < 4096) {                       // WT_in [128][32], k>=24 zero-pad
            int j = idx >> 5, k = idx & 31;
            WT_in[idx] = f2bf(k < PED ? W_in[k * HID + j] : 0.f);
        } else if (idx < 4096 + 16384) {
            int i = idx - 4096; int j = i >> 7, k = i & 127;
            WT1[i] = f2bf(W1[k * HID + j]);
        } else if (idx < 4096 + 32768) {
            int i = idx - 4096 - 16384; int j = i >> 7, k = i & 127;
            WT2[i] = f2bf(W2[k * HID + j]);
        } else if (idx < 4096 + 49152) {
            int i = idx - 4096 - 32768; int j = i >> 7, k = i & 127;
            WTf[i] = f2bf(Wf[k * HID + j]);
        }
    }
}

// ---------------------------------------------------------------------------
// CSR build: histogram(tgt) -> exclusive scan -> scatter edge ids
// ---------------------------------------------------------------------------
__global__ __launch_bounds__(256) void hist_kernel(const int* __restrict__ pe_idx,
                                                   int* __restrict__ cnt) {
    int e4 = blockIdx.x * 256 + threadIdx.x;
    if (e4 < EE / 4) {
        int4 t = *(const int4*)&pe_idx[e4 * 4];
        atomicAdd(&cnt[t.x], 1);
        atomicAdd(&cnt[t.y], 1);
        atomicAdd(&cnt[t.z], 1);
        atomicAdd(&cnt[t.w], 1);
    }
}

__global__ __launch_bounds__(1024) void scan_kernel(const int* __restrict__ cnt,
                                                    int* __restrict__ woff) {
    __shared__ int s_w[16];
    int tid = threadIdx.x;
    const int chunk = 52;            // 13 int4 per thread; 1024*52 covers 50000
    int base = tid * chunk;
    int end = base + chunk; if (end > NN) end = NN;
    int s = 0;
    if (base + chunk <= NN) {
#pragma unroll
        for (int i = 0; i < 13; i++) {
            int4 v4 = *(const int4*)&cnt[base + i * 4];
            s += v4.x + v4.y + v4.z + v4.w;
        }
    } else {
        for (int i = base; i < end; i++) s += cnt[i];
    }
    int v = s;
    int lane = tid & 63, wid = tid >> 6;
#pragma unroll
    for (int d = 1; d < 64; d <<= 1) {
        int u = __shfl_up(v, d, 64);
        if (lane >= d) v += u;
    }
    if (lane == 63) s_w[wid] = v;
    __syncthreads();
    if (tid < 16) {
        int wv = s_w[tid];
#pragma unroll
        for (int d = 1; d < 16; d <<= 1) {
            int u = __shfl_up(wv, d, 64);
            if (tid >= d) wv += u;
        }
        s_w[tid] = wv;
    }
    __syncthreads();
    int exc = v - s + (wid ? s_w[wid - 1] : 0);
    int run = exc;
    for (int i = base; i < end; i++) { woff[i] = run; run += cnt[i]; }
}

__global__ __launch_bounds__(256) void scatter_kernel(const int* __restrict__ pe_idx,
                                                      int* __restrict__ woff,
                                                      int* __restrict__ perm) {
    int e4 = blockIdx.x * 256 + threadIdx.x;
    if (e4 < EE / 4) {
        int4 t = *(const int4*)&pe_idx[e4 * 4];
        int e = e4 * 4;
        perm[atomicAdd(&woff[t.x], 1)] = e + 0;
        perm[atomicAdd(&woff[t.y], 1)] = e + 1;
        perm[atomicAdd(&woff[t.z], 1)] = e + 2;
        perm[atomicAdd(&woff[t.w], 1)] = e + 3;
    }
}

// ---------------------------------------------------------------------------
// Fused edge MLP (MFMA) + gather-multiply + CSR-sorted segment reduction.
// v7 (R6, best known -- UNCHANGED):
//  - s_pe side buffer for GEMM1 B-operand -> epi1 has no WAR -> one less
//    barrier (LDS 78.8 KB, 2 blocks/CU).
//  - single-pass wave-local walk: wave w owns edges [16w,16w+16), lane =
//    channel pair (u32 = 2 bf16). xh gathers prefetched after GEMM4 MFMAs.
//  - x0 packed bf16, bias in C-init, setprio around MFMA. 8 barriers.
// ---------------------------------------------------------------------------
__global__ __launch_bounds__(512, 4) void edge_kernel(
    const float* __restrict__ pe_val, const int* __restrict__ pe_idx,
    const int* __restrict__ perm, const unsigned short* __restrict__ xhb,
    const unsigned short* __restrict__ WT_in, const unsigned short* __restrict__ WT1,
    const unsigned short* __restrict__ WT2, const unsigned short* __restrict__ WTf,
    const float* __restrict__ b_in, const float* __restrict__ b1,
    const float* __restrict__ b2, const float* __restrict__ bfin,
    float* __restrict__ wV) {
    __shared__ __align__(16) unsigned short s_act[EBLK][AKS];   // 34.8 KB
    __shared__ __align__(16) unsigned short s_W[HID][AKS];      // 34.8 KB
    __shared__ __align__(16) unsigned short s_pe[EBLK][32];     // 8 KB
    __shared__ int s_tgt[EBLK], s_src[EBLK];

    const int tid = threadIdx.x;
    const int lane = tid & 63;
    const int w = tid >> 6;          // wave 0..7
    const int cg = w & 3;            // channel group (32 ch)
    const int eh = w >> 2;           // edge half (64 edges)
    const int ebase = eh * 64;
    const int l15 = lane & 15;
    const int quad = lane >> 4;
    const long b0 = (long)blockIdx.x * EBLK;

    if (tid < EBLK) {
        int eid = perm[b0 + tid];
        s_tgt[tid] = pe_idx[eid];
        s_src[tid] = pe_idx[EE + eid];
    }
    // stage W1 (used by GEMM2) -- disjoint LDS from pe staging, one barrier
#pragma unroll
    for (int i = 0; i < 4; i++) {
        int idx = tid + i * 512; int r = idx >> 4, seg = idx & 15;
        *(uint4*)&s_W[r][seg * 8] = *(const uint4*)&WT1[r * HID + seg * 8];
    }
    // stage pe (bf16 pairs) into s_pe cols 0..31 (24..31 zero); perm read
    // redundantly (16 threads/edge, same address -> L1/L2 broadcast)
#pragma unroll
    for (int i = 0; i < 4; i++) {
        int idx = tid + i * 512; int e = idx >> 4, k2 = idx & 15;
        float2 v = make_float2(0.f, 0.f);
        if (k2 < 12) {
            int eid = perm[b0 + e];
            v = *(const float2*)&pe_val[(size_t)eid * PED + k2 * 2];
        }
        *(unsigned int*)&s_pe[e][k2 * 2] = pkbf2(v.x, v.y);
    }
    __syncthreads();                                   // barrier A

    f32x4 C[2][4];
    uint2 x0pk[2][4];                // x0 saved as packed bf16 (16 regs)

    // ---- GEMM1: x0 = pe @ W_in + b_in  (K=32, B from s_pe, bias in C-init)
    {
        float4 ba = *(const float4*)&b_in[(2 * cg + 0) * 16 + quad * 4];
        float4 bb = *(const float4*)&b_in[(2 * cg + 1) * 16 + quad * 4];
        f32x4 ci0 = {ba.x, ba.y, ba.z, ba.w};
        f32x4 ci1 = {bb.x, bb.y, bb.z, bb.w};
        bf16x8 a0 = *(const bf16x8*)&WT_in[((2 * cg + 0) * 16 + l15) * 32 + quad * 8];
        bf16x8 a1 = *(const bf16x8*)&WT_in[((2 * cg + 1) * 16 + l15) * 32 + quad * 8];
        __builtin_amdgcn_s_setprio(1);
#pragma unroll
        for (int u = 0; u < 4; u++) {
            bf16x8 bfr = *(const bf16x8*)&s_pe[ebase + u * 16 + l15][quad * 8];
            C[0][u] = __builtin_amdgcn_mfma_f32_16x16x32_bf16(a0, bfr, ci0, 0, 0, 0);
            C[1][u] = __builtin_amdgcn_mfma_f32_16x16x32_bf16(a1, bfr, ci1, 0, 0, 0);
        }
        __builtin_amdgcn_s_setprio(0);
    }
    // epi1: save x0 packed, gelu -> act (act not yet read by anyone: no WAR)
#pragma unroll
    for (int t = 0; t < 2; t++) {
        int ch0 = (2 * cg + t) * 16 + quad * 4;
#pragma unroll
        for (int u = 0; u < 4; u++) {
            int e = ebase + u * 16 + l15;
            f32x4 c = C[t][u];
            x0pk[t][u].x = pkbf2(c[0], c[1]);
            x0pk[t][u].y = pkbf2(c[2], c[3]);
            uint2 p;
            p.x = pkbf2(gelu_fast(c[0]), gelu_fast(c[1]));
            p.y = pkbf2(gelu_fast(c[2]), gelu_fast(c[3]));
            *(uint2*)&s_act[e][ch0] = p;
        }
    }
    __syncthreads();                                   // barrier C (act ready)

#define GEMM128(BIAS)                                                          \
    {                                                                          \
        float4 ba_ = *(const float4*)&(BIAS)[(2 * cg + 0) * 16 + quad * 4];    \
        float4 bb_ = *(const float4*)&(BIAS)[(2 * cg + 1) * 16 + quad * 4];    \
        f32x4 ci0 = {ba_.x, ba_.y, ba_.z, ba_.w};                              \
        f32x4 ci1 = {bb_.x, bb_.y, bb_.z, bb_.w};                              \
        _Pragma("unroll") for (int u = 0; u < 4; u++) {                        \
            C[0][u] = ci0; C[1][u] = ci1;                                      \
        }                                                                      \
        __builtin_amdgcn_s_setprio(1);                                         \
        _Pragma("unroll") for (int ks = 0; ks < 4; ks++) {                     \
            bf16x8 a0 = *(const bf16x8*)&s_W[(2 * cg + 0) * 16 + l15]          \
                                            [ks * 32 + quad * 8];              \
            bf16x8 a1 = *(const bf16x8*)&s_W[(2 * cg + 1) * 16 + l15]          \
                                            [ks * 32 + quad * 8];              \
            _Pragma("unroll") for (int u = 0; u < 4; u++) {                    \
                bf16x8 bfr = *(const bf16x8*)&s_act[ebase + u * 16 + l15]      \
                                                   [ks * 32 + quad * 8];       \
                C[0][u] = __builtin_amdgcn_mfma_f32_16x16x32_bf16(a0, bfr,     \
                                                                  C[0][u], 0, 0, 0); \
                C[1][u] = __builtin_amdgcn_mfma_f32_16x16x32_bf16(a1, bfr,     \
                                                                  C[1][u], 0, 0, 0); \
            }                                                                  \
        }                                                                      \
        __builtin_amdgcn_s_setprio(0);                                         \
    }

#define STAGE_W(WT)                                                            \
    _Pragma("unroll") for (int i = 0; i < 4; i++) {                            \
        int idx = tid + i * 512; int r = idx >> 4, seg = idx & 15;             \
        *(uint4*)&s_W[r][seg * 8] = *(const uint4*)&(WT)[r * HID + seg * 8];   \
    }

    // ---- GEMM2: h1 = g(x0) @ W1 + b1 ; gelu -> act ; stage W2 ----
    GEMM128(b1);
    __syncthreads();                                   // barrier D
#pragma unroll
    for (int t = 0; t < 2; t++) {
        int ch0 = (2 * cg + t) * 16 + quad * 4;
#pragma unroll
        for (int u = 0; u < 4; u++) {
            int e = ebase + u * 16 + l15;
            f32x4 c = C[t][u];
            uint2 p;
            p.x = pkbf2(gelu_fast(c[0]), gelu_fast(c[1]));
            p.y = pkbf2(gelu_fast(c[2]), gelu_fast(c[3]));
            *(uint2*)&s_act[e][ch0] = p;
        }
    }
    STAGE_W(WT2);
    __syncthreads();                                   // barrier E

    // ---- GEMM3: h2 = g(h1) @ W2 + b2 ; x0' = h2 + x0 -> act ; stage Wf ----
    GEMM128(b2);
    __syncthreads();                                   // barrier F
#pragma unroll
    for (int t = 0; t < 2; t++) {
        int ch0 = (2 * cg + t) * 16 + quad * 4;
#pragma unroll
        for (int u = 0; u < 4; u++) {
            int e = ebase + u * 16 + l15;
            f32x4 c = C[t][u];
            uint2 p;
            p.x = pkbf2(c[0] + bflo(x0pk[t][u].x), c[1] + bfhi(x0pk[t][u].x));
            p.y = pkbf2(c[2] + bflo(x0pk[t][u].y), c[3] + bfhi(x0pk[t][u].y));
            *(uint2*)&s_act[e][ch0] = p;
        }
    }
    STAGE_W(WTf);
    __syncthreads();                                   // barrier G

    // ---- GEMM4: score = x0' @ W_fin + b_fin -> act (bf16) ----
    GEMM128(bfin);
    // prefetch xh gathers for the walk: wave w owns edges [16w, 16w+16),
    // lane = channel pair. 64 lanes x 4B = 256B/edge, coalesced. Issued
    // after GEMM4's MFMAs so latency hides under epi4 + barriers H,I.
    const int e0 = w * 16;
    unsigned int xv[16];
#pragma unroll
    for (int j = 0; j < 16; j++) {
        xv[j] = *(const unsigned int*)&xhb[(size_t)s_src[e0 + j] * HID + lane * 2];
    }
    __syncthreads();                                   // barrier H (GEMM4 reads done)
#pragma unroll
    for (int t = 0; t < 2; t++) {
        int ch0 = (2 * cg + t) * 16 + quad * 4;
#pragma unroll
        for (int u = 0; u < 4; u++) {
            int e = ebase + u * 16 + l15;
            f32x4 c = C[t][u];
            uint2 p;
            p.x = pkbf2(c[0], c[1]);
            p.y = pkbf2(c[2], c[3]);
            *(uint2*)&s_act[e][ch0] = p;
        }
    }
    __syncthreads();                                   // barrier I (scores ready)

    // ---- Single-pass wave-local segment walk ----
    // tg/prev are wave-uniform (LDS broadcast) -> uniform branch. Interior
    // segments: plain float2 store; boundary segments: 2x atomicAdd.
    {
        float a0 = 0.f, a1 = 0.f;
        int prev = s_tgt[e0];
        bool firstseg = true;
#pragma unroll
        for (int j = 0; j < 16; j++) {
            int tg = s_tgt[e0 + j];
            if (tg != prev) {
                float* wp = &wV[(size_t)prev * HID + lane * 2];
                if (firstseg) { atomicAdd(wp, a0); atomicAdd(wp + 1, a1); }
                else          { *(float2*)wp = make_float2(a0, a1); }
                firstseg = false;
                a0 = a1 = 0.f;
                prev = tg;
            }
            unsigned int sv = *(const unsigned int*)&s_act[e0 + j][lane * 2];
            unsigned int xu = xv[j];
            a0 += bflo(xu) * bflo(sv);
            a1 += bfhi(xu) * bfhi(sv);
        }
        float* wp = &wV[(size_t)prev * HID + lane * 2];
        atomicAdd(wp, a0); atomicAdd(wp + 1, a1);      // last seg may span blocks
    }
#undef GEMM128
#undef STAGE_W
}

// ---------------------------------------------------------------------------
// out = (wV / max(deg,1) + head_bias) @ W_out + b_out ; 4 outputs/thread
// v3 (R7): wr + head_bias loads vectorized to float4, bounded unroll 2.
// ---------------------------------------------------------------------------
__global__ __launch_bounds__(256) void out_kernel(
    const float* __restrict__ wV, const int* __restrict__ cnt,
    const float* __restrict__ head_bias, const float* __restrict__ W_out,
    const float* __restrict__ b_out, float* __restrict__ out) {
    int gid = blockIdx.x * 256 + threadIdx.x;
    int n = gid >> 4;
    int q = gid & 15;
    if (n >= NN) return;
    float inv = 1.0f / fmaxf((float)cnt[n], 1.0f);
    const float4* wr4p = (const float4*)(wV + (size_t)n * HID);
    const float4* hb4p = (const float4*)head_bias;
    float4 acc = *(const float4*)&b_out[q * 4];
#pragma unroll 2
    for (int k4 = 0; k4 < 32; k4++) {
        float4 wr4 = wr4p[k4];
        float4 hb4 = hb4p[k4];
        {
            float hv = __builtin_fmaf(wr4.x, inv, hb4.x);
            float4 w4 = *(const float4*)&W_out[(k4 * 4 + 0) * OUTD + q * 4];
            acc.x += hv * w4.x; acc.y += hv * w4.y;
            acc.z += hv * w4.z; acc.w += hv * w4.w;
        }
        {
            float hv = __builtin_fmaf(wr4.y, inv, hb4.y);
            float4 w4 = *(const float4*)&W_out[(k4 * 4 + 1) * OUTD + q * 4];
            acc.x += hv * w4.x; acc.y += hv * w4.y;
            acc.z += hv * w4.z; acc.w += hv * w4.w;
        }
        {
            float hv = __builtin_fmaf(wr4.z, inv, hb4.z);
            float4 w4 = *(const float4*)&W_out[(k4 * 4 + 2) * OUTD + q * 4];
            acc.x += hv * w4.x; acc.y += hv * w4.y;
            acc.z += hv * w4.z; acc.w += hv * w4.w;
        }
        {
            float hv = __builtin_fmaf(wr4.w, inv, hb4.w);
            float4 w4 = *(const float4*)&W_out[(k4 * 4 + 3) * OUTD + q * 4];
            acc.x += hv * w4.x; acc.y += hv * w4.y;
            acc.z += hv * w4.z; acc.w += hv * w4.w;
        }
    }
    *(float4*)&out[(size_t)n * OUTD + q * 4] = acc;
}

extern "C" void kernel_launch(void* const* d_in, const int* in_sizes, int n_in,
                              void* d_out, int out_size, void* d_ws, size_t ws_size,
                              hipStream_t stream) {
    const float* x      = (const float*)d_in[0];
    const int*   pe_idx = (const int*)d_in[1];
    const float* pe_val = (const float*)d_in[2];
    const float* W_in   = (const float*)d_in[3];
    const float* b_in   = (const float*)d_in[4];
    const float* W1     = (const float*)d_in[5];
    const float* b1     = (const float*)d_in[6];
    const float* W2     = (const float*)d_in[7];
    const float* b2     = (const float*)d_in[8];
    const float* Wf     = (const float*)d_in[9];
    const float* bfin   = (const float*)d_in[10];
    const float* W_x    = (const float*)d_in[11];
    const float* b_x    = (const float*)d_in[12];
    const float* hb     = (const float*)d_in[13];
    const float* W_out  = (const float*)d_in[14];
    const float* b_out  = (const float*)d_in[15];
    float* out = (float*)d_out;

    // ws layout:
    // wV f32 [N*128] | cnt i32 [N] | woff i32 [N] | perm i32 [E] |
    // WT_in u16 [4096] | WT1/WT2/WTf u16 [16384 each] | xhb u16 [N*128]
    float* wV   = (float*)d_ws;
    int*   cnt  = (int*)(wV + (size_t)NN * HID);
    int*   woff = cnt + NN;
    int*   perm = woff + NN;
    unsigned short* WT_in = (unsigned short*)(perm + EE);
    unsigned short* WT1   = WT_in + 128 * 32;
    unsigned short* WT2   = WT1 + 128 * 128;
    unsigned short* WTf   = WT2 + 128 * 128;
    unsigned short* xhb   = WTf + 128 * 128;

    pre_kernel<<<6250 + 208, 256, 0, stream>>>(x, W_x, b_x, xhb,
                                               W_in, W1, W2, Wf,
                                               WT_in, WT1, WT2, WTf, wV, cnt);
    hist_kernel<<<(EE / 4 + 255) / 256, 256, 0, stream>>>(pe_idx, cnt);
    scan_kernel<<<1, 1024, 0, stream>>>(cnt, woff);
    scatter_kernel<<<(EE / 4 + 255) / 256, 256, 0, stream>>>(pe_idx, woff, perm);

    edge_kernel<<<EE / EBLK, 512, 0, stream>>>(pe_val, pe_idx, perm, xhb,
                                               WT_in, WT1, WT2, WTf,
                                               b_in, b1, b2, bfin, wV);

    out_kernel<<<(NN * 16 + 255) / 256, 256, 0, stream>>>(wV, cnt, hb, W_out,
                                                          b_out, out);
}